// Round 7
// baseline (639.369 us; speedup 1.0000x reference)
//
#include <hip/hip_runtime.h>
#include <cstdint>
#include <cstddef>

typedef unsigned short u16;
typedef float f32x4 __attribute__((ext_vector_type(4)));
typedef short short8 __attribute__((ext_vector_type(8)));
typedef int i32x4 __attribute__((ext_vector_type(4)));

// ---------------- helpers ----------------

__device__ __forceinline__ float geluf(float v) {  // exact (libm erff)
  return 0.5f * v * (1.0f + erff(v * 0.70710678118654752440f));
}

// Abramowitz-Stegun 7.1.26: |err| <= 1.5e-7 abs. ~12 VALU inst (rcp+exp HW).
__device__ __forceinline__ float erf_fast(float x) {
  const float ax = fabsf(x);
  const float t = __builtin_amdgcn_rcpf(fmaf(0.3275911f, ax, 1.0f));
  float p = fmaf(1.061405429f, t, -1.453152027f);
  p = fmaf(p, t, 1.421413741f);
  p = fmaf(p, t, -0.284496736f);
  p = fmaf(p, t, 0.254829592f);
  p = p * t;
  const float e = __expf(-ax * ax);
  const float r = fmaf(-p, e, 1.0f);
  return copysignf(r, x);
}
__device__ __forceinline__ float gelu_fast(float v) {
  return 0.5f * v * (1.0f + erf_fast(v * 0.70710678118654752440f));
}

__device__ __forceinline__ u16 f2bf(float f) {  // RNE fp32 -> bf16 bits
  unsigned u = __float_as_uint(f);
  u = (u + 0x7FFFu + ((u >> 16) & 1u)) >> 16;
  return (u16)u;
}

__device__ __forceinline__ void waveRed2(float& s, float& s2) {
#pragma unroll
  for (int m = 1; m < 64; m <<= 1) {
    s += __shfl_xor(s, m);
    s2 += __shfl_xor(s2, m);
  }
}

// ---------------- LN over 512 (router input) ----------------
__global__ __launch_bounds__(256) void k_ln512(const float* __restrict__ x,
                                               const float* __restrict__ g,
                                               const float* __restrict__ b,
                                               float* __restrict__ out) {
  __shared__ float red[8];
  const int t = blockIdx.x, tid = threadIdx.x;
  const float v0 = x[(size_t)t * 512 + tid];
  const float v1 = x[(size_t)t * 512 + 256 + tid];
  float s = v0 + v1, s2 = v0 * v0 + v1 * v1;
  waveRed2(s, s2);
  if ((tid & 63) == 0) { red[(tid >> 6) * 2] = s; red[(tid >> 6) * 2 + 1] = s2; }
  __syncthreads();
  s = red[0] + red[2] + red[4] + red[6];
  s2 = red[1] + red[3] + red[5] + red[7];
  const float mu = s * (1.f / 512.f);
  const float var = fmaxf(s2 * (1.f / 512.f) - mu * mu, 0.f);
  const float rstd = 1.f / sqrtf(var + 1e-5f);
  out[(size_t)t * 512 + tid] = (v0 - mu) * rstd * g[tid] + b[tid];
  out[(size_t)t * 512 + 256 + tid] = (v1 - mu) * rstd * g[tid + 256] + b[tid + 256];
}

// ---------------- nvphi precompute: [2048,256] = nv@pW1[:128] + pb1 ----------------
__global__ __launch_bounds__(256) void k_nvphi(const float* __restrict__ nv,
                                               const float* __restrict__ pW1,
                                               const float* __restrict__ pb1,
                                               float* __restrict__ nvphi) {
  __shared__ float nvs[128];
  const int n = blockIdx.x, tid = threadIdx.x;
  if (tid < 128) nvs[tid] = nv[n * 128 + tid];
  __syncthreads();
  float s = pb1[tid];
#pragma unroll 4
  for (int i = 0; i < 128; ++i) s = fmaf(nvs[i], pW1[i * 256 + tid], s);
  nvphi[n * 256 + tid] = s;
}

// ---------------- pW2T[n][k] = bf16(pW2[k][n]) ----------------
__global__ __launch_bounds__(256) void k_pw2t(const float* __restrict__ pW2,
                                              u16* __restrict__ pW2T) {
  const int n = blockIdx.x, k = threadIdx.x;
  pW2T[n * 256 + k] = f2bf(pW2[k * 256 + n]);
}

// ---------------- 8x8-tile fp32 GEMM, C = act(A[M,K] @ B[N,K]^T) ----------------
// 128x128 block tile, KC=8. Threads <128 stage A rows, >=128 stage B rows
// (both K-contiguous), transposed scalar writes into As/Bs[k][row].
// GMODE: 0 none, 1 fast gelu, 2 precise gelu (score-critical h path).
template <int GMODE>
__global__ __launch_bounds__(256) void gemm8_bt(const float* __restrict__ A,
                                                const float* __restrict__ B,
                                                float* __restrict__ C, int M,
                                                int N, int K) {
  __shared__ float As[8][132];
  __shared__ float Bs[8][132];
  const int tid = threadIdx.x;
  const int tm = tid >> 4, tn = tid & 15;
  const int m0 = blockIdx.y * 128, n0 = blockIdx.x * 128;
  const bool isA = tid < 128;
  const int sr = isA ? tid : tid - 128;
  const float* gp = isA ? &A[(size_t)(m0 + sr) * K] : &B[(size_t)(n0 + sr) * K];
  float* sp = isA ? &As[0][sr] : &Bs[0][sr];
  float acc[8][8] = {};
  for (int k0 = 0; k0 < K; k0 += 8) {
    const float4 v0 = *(const float4*)&gp[k0];
    const float4 v1 = *(const float4*)&gp[k0 + 4];
    __syncthreads();  // previous iter's reads done before overwrite
    sp[0 * 132] = v0.x; sp[1 * 132] = v0.y; sp[2 * 132] = v0.z; sp[3 * 132] = v0.w;
    sp[4 * 132] = v1.x; sp[5 * 132] = v1.y; sp[6 * 132] = v1.z; sp[7 * 132] = v1.w;
    __syncthreads();
#pragma unroll
    for (int k = 0; k < 8; ++k) {
      float a[8], b[8];
      *(float4*)&a[0] = *(const float4*)&As[k][tm * 8];
      *(float4*)&a[4] = *(const float4*)&As[k][tm * 8 + 4];
      *(float4*)&b[0] = *(const float4*)&Bs[k][tn * 8];
      *(float4*)&b[4] = *(const float4*)&Bs[k][tn * 8 + 4];
#pragma unroll
      for (int i = 0; i < 8; ++i)
#pragma unroll
        for (int j = 0; j < 8; ++j) acc[i][j] = fmaf(a[i], b[j], acc[i][j]);
    }
  }
#pragma unroll
  for (int i = 0; i < 8; ++i) {
    float4 o0, o1;
    float* p0 = (float*)&o0;
    float* p1 = (float*)&o1;
#pragma unroll
    for (int j = 0; j < 4; ++j) {
      float xv = acc[i][j], yv = acc[i][j + 4];
      if (GMODE == 1) { xv = gelu_fast(xv); yv = gelu_fast(yv); }
      if (GMODE == 2) { xv = geluf(xv); yv = geluf(yv); }
      p0[j] = xv; p1[j] = yv;
    }
    float* cp = &C[(size_t)(m0 + tm * 8 + i) * N + n0 + tn * 8];
    *(float4*)cp = o0;
    *(float4*)(cp + 4) = o1;
  }
}

// ---------------- 8x8-tile fp32 GEMM, C = act(A[M,K] @ B[K,N] + bias) --------
template <int GMODE>
__global__ __launch_bounds__(256) void gemm8_bn(const float* __restrict__ A,
                                                const float* __restrict__ B,
                                                const float* __restrict__ bias,
                                                float* __restrict__ C, int M,
                                                int N, int K) {
  __shared__ float As[8][132];
  __shared__ float Bs[8][132];
  const int tid = threadIdx.x;
  const int tm = tid >> 4, tn = tid & 15;
  const int m0 = blockIdx.y * 128, n0 = blockIdx.x * 128;
  const bool isA = tid < 128;
  const int sr = isA ? tid : tid - 128;
  const int bk = (tid - 128) >> 4, bn8 = ((tid - 128) & 15) * 8;
  const float* gpA = &A[(size_t)(m0 + sr) * K];
  float* spA = &As[0][sr];
  float acc[8][8] = {};
  for (int k0 = 0; k0 < K; k0 += 8) {
    float4 v0, v1;
    if (isA) {
      v0 = *(const float4*)&gpA[k0];
      v1 = *(const float4*)&gpA[k0 + 4];
    } else {
      v0 = *(const float4*)&B[(size_t)(k0 + bk) * N + n0 + bn8];
      v1 = *(const float4*)&B[(size_t)(k0 + bk) * N + n0 + bn8 + 4];
    }
    __syncthreads();
    if (isA) {
      spA[0 * 132] = v0.x; spA[1 * 132] = v0.y; spA[2 * 132] = v0.z; spA[3 * 132] = v0.w;
      spA[4 * 132] = v1.x; spA[5 * 132] = v1.y; spA[6 * 132] = v1.z; spA[7 * 132] = v1.w;
    } else {
      *(float4*)&Bs[bk][bn8] = v0;
      *(float4*)&Bs[bk][bn8 + 4] = v1;
    }
    __syncthreads();
#pragma unroll
    for (int k = 0; k < 8; ++k) {
      float a[8], b[8];
      *(float4*)&a[0] = *(const float4*)&As[k][tm * 8];
      *(float4*)&a[4] = *(const float4*)&As[k][tm * 8 + 4];
      *(float4*)&b[0] = *(const float4*)&Bs[k][tn * 8];
      *(float4*)&b[4] = *(const float4*)&Bs[k][tn * 8 + 4];
#pragma unroll
      for (int i = 0; i < 8; ++i)
#pragma unroll
        for (int j = 0; j < 8; ++j) acc[i][j] = fmaf(a[i], b[j], acc[i][j]);
    }
  }
  const float4 bb0 = *(const float4*)&bias[n0 + tn * 8];
  const float4 bb1 = *(const float4*)&bias[n0 + tn * 8 + 4];
  const float* bbp0 = (const float*)&bb0;
  const float* bbp1 = (const float*)&bb1;
#pragma unroll
  for (int i = 0; i < 8; ++i) {
    float4 o0, o1;
    float* p0 = (float*)&o0;
    float* p1 = (float*)&o1;
#pragma unroll
    for (int j = 0; j < 4; ++j) {
      float xv = acc[i][j] + bbp0[j], yv = acc[i][j + 4] + bbp1[j];
      if (GMODE == 1) { xv = gelu_fast(xv); yv = gelu_fast(yv); }
      if (GMODE == 2) { xv = geluf(xv); yv = geluf(yv); }
      p0[j] = xv; p1[j] = yv;
    }
    float* cp = &C[(size_t)(m0 + tm * 8 + i) * N + n0 + tn * 8];
    *(float4*)cp = o0;
    *(float4*)(cp + 4) = o1;
  }
}

// ---------------- top-64 of 2048 scores per token ----------------
__global__ __launch_bounds__(256) void k_topk(const float* __restrict__ scores,
                                              int* __restrict__ idxout) {
  __shared__ int redc[4];
  __shared__ unsigned cg_cnt, ec;
  __shared__ int eqbuf[64];
  const int t = blockIdx.x, tid = threadIdx.x;
  unsigned key[8];
#pragma unroll
  for (int j = 0; j < 8; ++j) {
    const unsigned u = __float_as_uint(scores[(size_t)t * 2048 + tid + 256 * j]);
    key[j] = (u & 0x80000000u) ? ~u : (u | 0x80000000u);
  }
  unsigned lo = 0u, hi = 0xFFFFFFFFu;
  while (lo < hi) {
    const unsigned mid = (unsigned)(((unsigned long long)lo + hi + 1ull) >> 1);
    int c = 0;
#pragma unroll
    for (int j = 0; j < 8; ++j) c += (key[j] >= mid);
#pragma unroll
    for (int m = 1; m < 64; m <<= 1) c += __shfl_xor(c, m);
    if ((tid & 63) == 0) redc[tid >> 6] = c;
    __syncthreads();
    const int total = redc[0] + redc[1] + redc[2] + redc[3];
    __syncthreads();
    if (total >= 64) lo = mid; else hi = mid - 1;
  }
  if (tid == 0) { cg_cnt = 0u; ec = 0u; }
  __syncthreads();
#pragma unroll
  for (int j = 0; j < 8; ++j) {
    if (key[j] > lo) {
      const unsigned pos = atomicAdd(&cg_cnt, 1u);
      idxout[(size_t)t * 64 + pos] = tid + 256 * j;
    } else if (key[j] == lo) {
      const unsigned e = atomicAdd(&ec, 1u);
      if (e < 64u) eqbuf[e] = tid + 256 * j;
    }
  }
  __syncthreads();
  if (tid == 0) {
    const int cg = (int)cg_cnt;
    int ne = (int)ec; if (ne > 64) ne = 64;
    const int need = 64 - cg;
    for (int i = 1; i < ne; ++i) {
      const int v = eqbuf[i];
      int j = i - 1;
      while (j >= 0 && eqbuf[j] > v) { eqbuf[j + 1] = eqbuf[j]; --j; }
      eqbuf[j + 1] = v;
    }
    for (int i = 0; i < need; ++i) idxout[(size_t)t * 64 + cg + i] = eqbuf[i];
  }
}

// ---------------- act[t][k] = gelu(dot(x[t], W_in[idx[t][k]])) ----------------
__global__ __launch_bounds__(256) void k_act(const float* __restrict__ x,
                                             const float* __restrict__ W_in,
                                             const int* __restrict__ idx,
                                             float* __restrict__ act) {
  __shared__ float xs[512];
  const int t = blockIdx.x, tid = threadIdx.x;
  xs[tid] = x[(size_t)t * 512 + tid];
  xs[tid + 256] = x[(size_t)t * 512 + 256 + tid];
  __syncthreads();
  const int w = tid >> 6, l = tid & 63;
  for (int q = 0; q < 16; ++q) {
    const int k = w * 16 + q;
    const int n = idx[(size_t)t * 64 + k];
    const float* Wr = W_in + (size_t)n * 512;
    float s = 0.f;
#pragma unroll
    for (int j = 0; j < 8; ++j) s = fmaf(Wr[l + 64 * j], xs[l + 64 * j], s);
#pragma unroll
    for (int m = 1; m < 64; m <<= 1) s += __shfl_xor(s, m);
    if (l == 0) act[(size_t)t * 64 + k] = gelu_fast(s);
  }
}

// ---------------- fused phi, MFMA version (one token per block) ----------------
// All register-array indices compile-time (R2/R5 spill lesson).
__global__ __launch_bounds__(256, 1) void k_phi(
    const float* __restrict__ nvphi, const float* __restrict__ pW1,
    const float* __restrict__ pln1_g, const float* __restrict__ pln1_b,
    const u16* __restrict__ pW2T, const float* __restrict__ pb2,
    const float* __restrict__ pln2_g, const float* __restrict__ pln2_b,
    const int* __restrict__ idx, const float* __restrict__ act,
    float* __restrict__ aggp) {
  __shared__ __align__(16) u16 h1s[64 * 264];
  __shared__ __align__(16) u16 Bs[64 * 264];
  __shared__ float aggbuf[4 * 256];
  __shared__ int idxs[64];
  __shared__ float acts[64];
  const int tid = threadIdx.x;
  const int t = blockIdx.x;
  const int w = tid >> 6, lane = tid & 63;
  const int q = lane >> 4, c = lane & 15;
  if (tid < 64) {
    idxs[tid] = idx[(size_t)t * 64 + tid];
    acts[tid] = act[(size_t)t * 64 + tid];
  }
  __syncthreads();
  // ---- Phase A ----
  {
    f32x4 w4[4], g1[4], b1[4];
#pragma unroll
    for (int j = 0; j < 4; ++j) {
      w4[j] = *(const f32x4*)&pW1[128 * 256 + c * 16 + j * 4];
      g1[j] = *(const f32x4*)&pln1_g[c * 16 + j * 4];
      b1[j] = *(const f32x4*)&pln1_b[c * 16 + j * 4];
    }
#pragma unroll 1
    for (int rd = 0; rd < 4; ++rd) {
      const int p = w * 16 + rd * 4 + q;
      const int n = idxs[p];
      const float av = acts[p];
      f32x4 v[4];
      float s = 0.f, s2 = 0.f;
#pragma unroll
      for (int j = 0; j < 4; ++j) {
        const f32x4 nv = *(const f32x4*)&nvphi[(size_t)n * 256 + c * 16 + j * 4];
#pragma unroll
        for (int u = 0; u < 4; ++u) {
          v[j][u] = nv[u] + av * w4[j][u];
          s += v[j][u];
          s2 = fmaf(v[j][u], v[j][u], s2);
        }
      }
#pragma unroll
      for (int m = 1; m < 16; m <<= 1) { s += __shfl_xor(s, m); s2 += __shfl_xor(s2, m); }
      const float mu = s * (1.f / 256.f);
      const float var = fmaxf(s2 * (1.f / 256.f) - mu * mu, 0.f);
      const float rstd = 1.f / sqrtf(var + 1e-5f);
      short8 lo, hi;
#pragma unroll
      for (int j = 0; j < 4; ++j)
#pragma unroll
        for (int u = 0; u < 4; ++u) {
          const float hv = gelu_fast((v[j][u] - mu) * rstd * g1[j][u] + b1[j][u]);
          if (j < 2) lo[j * 4 + u] = (short)f2bf(hv);
          else       hi[(j - 2) * 4 + u] = (short)f2bf(hv);
        }
      *(short8*)&h1s[p * 264 + c * 16] = lo;
      *(short8*)&h1s[p * 264 + c * 16 + 8] = hi;
    }
  }
  __syncthreads();
  short8 afr[8];
#pragma unroll
  for (int ks = 0; ks < 8; ++ks)
    afr[ks] = *(const short8*)&h1s[(w * 16 + c) * 264 + ks * 32 + q * 8];
  f32x4 acc[16];
#pragma unroll
  for (int nt = 0; nt < 16; ++nt) {
    const float bz = pb2[nt * 16 + c];
    acc[nt] = (f32x4){bz, bz, bz, bz};
  }
  // ---- Phase B (ch fully unrolled: keep acc indices compile-time) ----
#pragma unroll
  for (int ch = 0; ch < 4; ++ch) {
    __syncthreads();
#pragma unroll
    for (int i = 0; i < 8; ++i) {
      const int cidx = i * 256 + tid;
      const int n = cidx >> 5, kc = cidx & 31;
      *(i32x4*)&Bs[n * 264 + kc * 8] =
          *(const i32x4*)&pW2T[(size_t)(ch * 64 + n) * 256 + kc * 8];
    }
    __syncthreads();
#pragma unroll
    for (int t4 = 0; t4 < 4; ++t4) {
      const int nt = ch * 4 + t4;
#pragma unroll
      for (int ks = 0; ks < 8; ++ks) {
        const short8 bfr = *(const short8*)&Bs[(t4 * 16 + c) * 264 + ks * 32 + q * 8];
        acc[nt] = __builtin_amdgcn_mfma_f32_16x16x32_bf16(afr[ks], bfr, acc[nt], 0, 0, 0);
      }
    }
  }
  // ---- Phase C ----
  float g2v[16], b2v[16];
#pragma unroll
  for (int nt = 0; nt < 16; ++nt) {
    g2v[nt] = pln2_g[nt * 16 + c];
    b2v[nt] = pln2_b[nt * 16 + c];
  }
  float aggl[16];
#pragma unroll
  for (int nt = 0; nt < 16; ++nt) aggl[nt] = 0.f;
#pragma unroll
  for (int reg = 0; reg < 4; ++reg) {
    float s = 0.f, s2 = 0.f;
#pragma unroll
    for (int nt = 0; nt < 16; ++nt) {
      const float vv = acc[nt][reg];
      s += vv;
      s2 = fmaf(vv, vv, s2);
    }
#pragma unroll
    for (int m = 1; m < 16; m <<= 1) { s += __shfl_xor(s, m); s2 += __shfl_xor(s2, m); }
    const float mu = s * (1.f / 256.f);
    const float var = fmaxf(s2 * (1.f / 256.f) - mu * mu, 0.f);
    const float rstd = 1.f / sqrtf(var + 1e-5f);
#pragma unroll
    for (int nt = 0; nt < 16; ++nt) {
      const float vv = acc[nt][reg];
      aggl[nt] += (vv - mu) * rstd * g2v[nt] + b2v[nt];
    }
  }
#pragma unroll
  for (int nt = 0; nt < 16; ++nt) {
    float vs = aggl[nt];
    vs += __shfl_xor(vs, 16);
    vs += __shfl_xor(vs, 32);
    if (q == 0) aggbuf[w * 256 + nt * 16 + c] = vs;
  }
  __syncthreads();
  aggp[(size_t)t * 256 + tid] =
      aggbuf[tid] + aggbuf[256 + tid] + aggbuf[512 + tid] + aggbuf[768 + tid];
}

// ---------------- r = LN(aggp[t]) over 256 ----------------
__global__ __launch_bounds__(256) void k_rln(const float* __restrict__ aggp,
                                             const float* __restrict__ g,
                                             const float* __restrict__ b,
                                             float* __restrict__ r) {
  __shared__ float red[8];
  const int t = blockIdx.x, tid = threadIdx.x;
  const float v = aggp[(size_t)t * 256 + tid];
  float s = v, s2 = v * v;
  waveRed2(s, s2);
  if ((tid & 63) == 0) { red[(tid >> 6) * 2] = s; red[(tid >> 6) * 2 + 1] = s2; }
  __syncthreads();
  s = red[0] + red[2] + red[4] + red[6];
  s2 = red[1] + red[3] + red[5] + red[7];
  const float mu = s * (1.f / 256.f);
  const float var = fmaxf(s2 * (1.f / 256.f) - mu * mu, 0.f);
  const float rstd = 1.f / sqrtf(var + 1e-5f);
  r[(size_t)t * 256 + tid] = (v - mu) * rstd * g[tid] + b[tid];
}

// ---------------- launch ----------------
extern "C" void kernel_launch(void* const* d_in, const int* in_sizes, int n_in,
                              void* d_out, int out_size, void* d_ws, size_t ws_size,
                              hipStream_t stream) {
  const float* x = (const float*)d_in[0];
  const float* W_in = (const float*)d_in[1];
  const float* nv = (const float*)d_in[2];
  const float* Wr1 = (const float*)d_in[3];
  const float* Wr2 = (const float*)d_in[4];
  const float* rn_g = (const float*)d_in[5];
  const float* rn_b = (const float*)d_in[6];
  const float* pW1 = (const float*)d_in[7];
  const float* pb1 = (const float*)d_in[8];
  const float* pln1_g = (const float*)d_in[9];
  const float* pln1_b = (const float*)d_in[10];
  const float* pW2 = (const float*)d_in[11];
  const float* pb2 = (const float*)d_in[12];
  const float* pln2_g = (const float*)d_in[13];
  const float* pln2_b = (const float*)d_in[14];
  const float* rln_g = (const float*)d_in[15];
  const float* rln_b = (const float*)d_in[16];
  const float* rW1 = (const float*)d_in[17];
  const float* rb1 = (const float*)d_in[18];
  const float* rW2 = (const float*)d_in[19];
  const float* rb2 = (const float*)d_in[20];
  float* out = (float*)d_out;
  const int T = in_sizes[0] / 512;  // 4096

  float* ws = (float*)d_ws;
  float* xln = ws;    ws += (size_t)T * 512;
  float* h = ws;      ws += (size_t)T * 512;
  float* scores = ws; ws += (size_t)T * 2048;
  float* nvphi = ws;  ws += (size_t)2048 * 256;
  float* actb = ws;   ws += (size_t)T * 64;
  float* aggp = ws;   ws += (size_t)T * 256;
  float* rbuf = ws;   ws += (size_t)T * 256;
  float* t1 = ws;     ws += (size_t)T * 512;
  int* idx = (int*)ws; ws += (size_t)T * 64;
  u16* pW2T = (u16*)ws;

  k_nvphi<<<2048, 256, 0, stream>>>(nv, pW1, pb1, nvphi);
  k_pw2t<<<256, 256, 0, stream>>>(pW2, pW2T);
  k_ln512<<<T, 256, 0, stream>>>(x, rn_g, rn_b, xln);
  // h = gelu(xln @ Wr1^T)   [precise gelu: score-critical path]
  gemm8_bt<2><<<dim3(512 / 128, T / 128), 256, 0, stream>>>(xln, Wr1, h, T, 512, 512);
  // scores = h @ Wr2^T
  gemm8_bt<0><<<dim3(2048 / 128, T / 128), 256, 0, stream>>>(h, Wr2, scores, T, 2048, 512);
  k_topk<<<T, 256, 0, stream>>>(scores, idx);
  k_act<<<T, 256, 0, stream>>>(x, W_in, idx, actb);
  k_phi<<<T, 256, 0, stream>>>(nvphi, pW1, pln1_g, pln1_b, pW2T, pb2, pln2_g,
                               pln2_b, idx, actb, aggp);
  k_rln<<<T, 256, 0, stream>>>(aggp, rln_g, rln_b, rbuf);
  // rho
  gemm8_bn<1><<<dim3(512 / 128, T / 128), 256, 0, stream>>>(rbuf, rW1, rb1, t1, T, 512, 256);
  gemm8_bn<0><<<dim3(512 / 128, T / 128), 256, 0, stream>>>(t1, rW2, rb2, out, T, 512, 512);
}

// Round 9
// 500.702 us; speedup vs baseline: 1.2769x; 1.2769x over previous
//
#include <hip/hip_runtime.h>
#include <cstdint>
#include <cstddef>

typedef unsigned short u16;
typedef float f32x4 __attribute__((ext_vector_type(4)));
typedef short short8 __attribute__((ext_vector_type(8)));
typedef int i32x4 __attribute__((ext_vector_type(4)));

// ---------------- helpers ----------------

__device__ __forceinline__ float geluf(float v) {  // exact (libm erff)
  return 0.5f * v * (1.0f + erff(v * 0.70710678118654752440f));
}

// Abramowitz-Stegun 7.1.26: |err| <= 1.5e-7 abs.
__device__ __forceinline__ float erf_fast(float x) {
  const float ax = fabsf(x);
  const float t = __builtin_amdgcn_rcpf(fmaf(0.3275911f, ax, 1.0f));
  float p = fmaf(1.061405429f, t, -1.453152027f);
  p = fmaf(p, t, 1.421413741f);
  p = fmaf(p, t, -0.284496736f);
  p = fmaf(p, t, 0.254829592f);
  p = p * t;
  const float e = __expf(-ax * ax);
  const float r = fmaf(-p, e, 1.0f);
  return copysignf(r, x);
}
__device__ __forceinline__ float gelu_fast(float v) {
  return 0.5f * v * (1.0f + erf_fast(v * 0.70710678118654752440f));
}

__device__ __forceinline__ u16 f2bf(float f) {  // RNE fp32 -> bf16 bits
  unsigned u = __float_as_uint(f);
  u = (u + 0x7FFFu + ((u >> 16) & 1u)) >> 16;
  return (u16)u;
}
__device__ __forceinline__ float bf2f(u16 h) {
  return __uint_as_float(((unsigned)h) << 16);
}

__device__ __forceinline__ void waveRed2(float& s, float& s2) {
#pragma unroll
  for (int m = 1; m < 64; m <<= 1) {
    s += __shfl_xor(s, m);
    s2 += __shfl_xor(s2, m);
  }
}

// ---------------- LN over 512 (fp32 out — score-critical) ----------------
__global__ __launch_bounds__(256) void k_ln512(const float* __restrict__ x,
                                               const float* __restrict__ g,
                                               const float* __restrict__ b,
                                               float* __restrict__ out) {
  __shared__ float red[8];
  const int t = blockIdx.x, tid = threadIdx.x;
  const float v0 = x[(size_t)t * 512 + tid];
  const float v1 = x[(size_t)t * 512 + 256 + tid];
  float s = v0 + v1, s2 = v0 * v0 + v1 * v1;
  waveRed2(s, s2);
  if ((tid & 63) == 0) { red[(tid >> 6) * 2] = s; red[(tid >> 6) * 2 + 1] = s2; }
  __syncthreads();
  s = red[0] + red[2] + red[4] + red[6];
  s2 = red[1] + red[3] + red[5] + red[7];
  const float mu = s * (1.f / 512.f);
  const float var = fmaxf(s2 * (1.f / 512.f) - mu * mu, 0.f);
  const float rstd = 1.f / sqrtf(var + 1e-5f);
  out[(size_t)t * 512 + tid] = (v0 - mu) * rstd * g[tid] + b[tid];
  out[(size_t)t * 512 + 256 + tid] = (v1 - mu) * rstd * g[tid + 256] + b[tid + 256];
}

// ---------------- elementwise fp32 -> bf16 ----------------
__global__ __launch_bounds__(256) void k_cvt(const float* __restrict__ in,
                                             u16* __restrict__ o) {
  const int i = blockIdx.x * 256 + threadIdx.x;
  o[i] = f2bf(in[i]);
}

// ---------------- split-transpose: outT[n][k] = split(in[k][n]) ----------------
__global__ __launch_bounds__(256) void k_splitT(const float* __restrict__ in,
                                                u16* __restrict__ hiT,
                                                u16* __restrict__ loT, int R,
                                                int Cc) {
  const int n = blockIdx.x;
  for (int k = threadIdx.x; k < R; k += 256) {
    const float v = in[(size_t)k * Cc + n];
    const u16 h = f2bf(v);
    hiT[(size_t)n * R + k] = h;
    loT[(size_t)n * R + k] = f2bf(v - bf2f(h));
  }
}

// ---------------- nvphi precompute: [2048,256] = nv@pW1[:128] + pb1 ----------------
__global__ __launch_bounds__(256) void k_nvphi(const float* __restrict__ nv,
                                               const float* __restrict__ pW1,
                                               const float* __restrict__ pb1,
                                               float* __restrict__ nvphi) {
  __shared__ float nvs[128];
  const int n = blockIdx.x, tid = threadIdx.x;
  if (tid < 128) nvs[tid] = nv[n * 128 + tid];
  __syncthreads();
  float s = pb1[tid];
#pragma unroll 4
  for (int i = 0; i < 128; ++i) s = fmaf(nvs[i], pW1[i * 256 + tid], s);
  nvphi[n * 256 + tid] = s;
}

// ---------------- pW2T[n][k] = bf16(pW2[k][n]) ----------------
__global__ __launch_bounds__(256) void k_pw2t(const float* __restrict__ pW2,
                                              u16* __restrict__ pW2T) {
  const int n = blockIdx.x, k = threadIdx.x;
  pW2T[n * 256 + k] = f2bf(pW2[k * 256 + n]);
}

// ---------------- 64-tile fp32 GEMM, C = act(A[M,K] @ B[N,K]^T) ----------------
// Known-good from R6. GMODE: 0 none, 2 precise gelu. BF16OUT: also emit bf16 C.
template <int GMODE, bool BF16OUT>
__global__ __launch_bounds__(256) void gemm_bt(const float* __restrict__ A,
                                               const float* __restrict__ B,
                                               float* __restrict__ C,
                                               u16* __restrict__ Cb, int M,
                                               int N, int K) {
  __shared__ float As[16][68];
  __shared__ float Bs[16][68];
  const int tid = threadIdx.x;
  const int tn = tid & 15, tm = tid >> 4;
  const int m0 = blockIdx.y * 64, n0 = blockIdx.x * 64;
  const int lr = tid >> 2, lk = (tid & 3) << 2;
  float acc[4][4] = {};
  for (int k0 = 0; k0 < K; k0 += 16) {
    const float4 av = *(const float4*)&A[(size_t)(m0 + lr) * K + k0 + lk];
    const float4 bv = *(const float4*)&B[(size_t)(n0 + lr) * K + k0 + lk];
    As[lk + 0][lr] = av.x; As[lk + 1][lr] = av.y; As[lk + 2][lr] = av.z; As[lk + 3][lr] = av.w;
    Bs[lk + 0][lr] = bv.x; Bs[lk + 1][lr] = bv.y; Bs[lk + 2][lr] = bv.z; Bs[lk + 3][lr] = bv.w;
    __syncthreads();
#pragma unroll
    for (int k = 0; k < 16; ++k) {
      float a[4], b[4];
      *(float4*)a = *(const float4*)&As[k][tm * 4];
      *(float4*)b = *(const float4*)&Bs[k][tn * 4];
#pragma unroll
      for (int i = 0; i < 4; ++i)
#pragma unroll
        for (int j = 0; j < 4; ++j) acc[i][j] = fmaf(a[i], b[j], acc[i][j]);
    }
    __syncthreads();
  }
#pragma unroll
  for (int i = 0; i < 4; ++i) {
    float4 v;
    float* vp = (float*)&v;
#pragma unroll
    for (int j = 0; j < 4; ++j) {
      float xv = acc[i][j];
      if (GMODE == 2) xv = geluf(xv);
      vp[j] = xv;
    }
    const size_t off = (size_t)(m0 + tm * 4 + i) * N + n0 + tn * 4;
    *(float4*)&C[off] = v;
    if (BF16OUT) {
      ushort4 ob;
      ob.x = f2bf(vp[0]); ob.y = f2bf(vp[1]); ob.z = f2bf(vp[2]); ob.w = f2bf(vp[3]);
      *(ushort4*)&Cb[off] = ob;
    }
  }
}

// ---------------- MFMA GEMM: C = act(A[M,K] @ B[N,K]^T + bias) ----------------
// 64x128 tile, BK=32. OUT: 0 fp32, 1 bf16, 2 split hi/lo. GMODE: 0/1 fast.
// All register-array indices compile-time (spill lesson R2/R5).
template <bool SPLIT, int GMODE, bool BIAS, int OUT>
__global__ __launch_bounds__(256) void gemm_mf(
    const u16* __restrict__ Ahi, const u16* __restrict__ Alo,
    const u16* __restrict__ Bhi, const u16* __restrict__ Blo,
    const float* __restrict__ bias, void* __restrict__ Cp,
    void* __restrict__ C2p, int M, int N, int K) {
  constexpr int ASZ = 64 * 40;
  constexpr int BSZ = 128 * 40;
  __shared__ __align__(16) u16 smem[(SPLIT ? 2 : 1) * (ASZ + BSZ)];
  u16* sAh = smem;
  u16* sBh = smem + (SPLIT ? 2 : 1) * ASZ;
  u16* sAl = SPLIT ? (smem + ASZ) : nullptr;
  u16* sBl = SPLIT ? (sBh + BSZ) : nullptr;

  const int tid = threadIdx.x;
  const int w = tid >> 6, lane = tid & 63;
  const int q = lane >> 4, c = lane & 15;
  const int m0 = blockIdx.y * 64, n0 = blockIdx.x * 128;
  const int ra = tid >> 2, ka = (tid & 3) * 8;
  const int rb = tid >> 1, kb = (tid & 1) * 16;
  const u16* gAh = Ahi + (size_t)(m0 + ra) * K + ka;
  const u16* gBh = Bhi + (size_t)(n0 + rb) * K + kb;
  const u16* gAl = SPLIT ? (Alo + (size_t)(m0 + ra) * K + ka) : nullptr;
  const u16* gBl = SPLIT ? (Blo + (size_t)(n0 + rb) * K + kb) : nullptr;

  f32x4 acc[8];
#pragma unroll
  for (int ct = 0; ct < 8; ++ct) {
    const float bv = BIAS ? bias[n0 + ct * 16 + c] : 0.f;
    acc[ct] = (f32x4){bv, bv, bv, bv};
  }

  for (int k0 = 0; k0 < K; k0 += 32) {
    const i32x4 vah = *(const i32x4*)(gAh + k0);
    const i32x4 vbh0 = *(const i32x4*)(gBh + k0);
    const i32x4 vbh1 = *(const i32x4*)(gBh + k0 + 8);
    i32x4 val, vbl0, vbl1;
    if (SPLIT) {
      val = *(const i32x4*)(gAl + k0);
      vbl0 = *(const i32x4*)(gBl + k0);
      vbl1 = *(const i32x4*)(gBl + k0 + 8);
    }
    __syncthreads();
    *(i32x4*)&sAh[ra * 40 + ka] = vah;
    *(i32x4*)&sBh[rb * 40 + kb] = vbh0;
    *(i32x4*)&sBh[rb * 40 + kb + 8] = vbh1;
    if (SPLIT) {
      *(i32x4*)&sAl[ra * 40 + ka] = val;
      *(i32x4*)&sBl[rb * 40 + kb] = vbl0;
      *(i32x4*)&sBl[rb * 40 + kb + 8] = vbl1;
    }
    __syncthreads();
    const int abase = (w * 16 + c) * 40 + q * 8;
    const short8 ah = *(const short8*)&sAh[abase];
    short8 al;
    if (SPLIT) al = *(const short8*)&sAl[abase];
#pragma unroll
    for (int ct = 0; ct < 8; ++ct) {
      const int bbase = (ct * 16 + c) * 40 + q * 8;
      const short8 bh = *(const short8*)&sBh[bbase];
      acc[ct] = __builtin_amdgcn_mfma_f32_16x16x32_bf16(ah, bh, acc[ct], 0, 0, 0);
      if (SPLIT) {
        const short8 bl = *(const short8*)&sBl[bbase];
        acc[ct] = __builtin_amdgcn_mfma_f32_16x16x32_bf16(al, bh, acc[ct], 0, 0, 0);
        acc[ct] = __builtin_amdgcn_mfma_f32_16x16x32_bf16(ah, bl, acc[ct], 0, 0, 0);
      }
    }
  }
#pragma unroll
  for (int ct = 0; ct < 8; ++ct) {
#pragma unroll
    for (int reg = 0; reg < 4; ++reg) {
      float v = acc[ct][reg];
      if (GMODE == 1) v = gelu_fast(v);
      const size_t off = (size_t)(m0 + w * 16 + q * 4 + reg) * N + n0 + ct * 16 + c;
      if (OUT == 0) {
        ((float*)Cp)[off] = v;
      } else if (OUT == 1) {
        ((u16*)Cp)[off] = f2bf(v);
      } else {
        const u16 hv = f2bf(v);
        ((u16*)Cp)[off] = hv;
        ((u16*)C2p)[off] = f2bf(v - bf2f(hv));
      }
    }
  }
}

// ---------------- top-64 via approx candidates + exact fp32 rescore ----------------
// 1) top-96 candidates from bf16-MFMA approx scores (margin 32 ranks >> 100x
//    the bf16 score error). 2) exact fp32 rescore vs h,Wr2. 3) exact top-64,
//    ties -> lowest index (np semantics).
__global__ __launch_bounds__(256) void k_topk_rs(
    const u16* __restrict__ scoresb, const float* __restrict__ h,
    const float* __restrict__ Wr2, int* __restrict__ idxout) {
  __shared__ float hs[512];
  __shared__ int redc[4];
  __shared__ int cand[160];
  __shared__ float cex[160];
  __shared__ unsigned ccnt, cg_cnt, ec;
  __shared__ int eqbuf[64];
  const int t = blockIdx.x, tid = threadIdx.x;
  hs[tid] = h[(size_t)t * 512 + tid];
  hs[tid + 256] = h[(size_t)t * 512 + 256 + tid];
  unsigned key[8];
#pragma unroll
  for (int j = 0; j < 8; ++j) {
    const unsigned u = ((unsigned)scoresb[(size_t)t * 2048 + tid + 256 * j]) << 16;
    key[j] = (u & 0x80000000u) ? ~u : (u | 0x80000000u);
  }
  if (tid == 0) ccnt = 0u;
  unsigned lo = 0u, hi = 0xFFFFFFFFu;
  while (lo < hi) {
    const unsigned mid = (unsigned)(((unsigned long long)lo + hi + 1ull) >> 1);
    int c = 0;
#pragma unroll
    for (int j = 0; j < 8; ++j) c += (key[j] >= mid);
#pragma unroll
    for (int m = 1; m < 64; m <<= 1) c += __shfl_xor(c, m);
    if ((tid & 63) == 0) redc[tid >> 6] = c;
    __syncthreads();
    const int total = redc[0] + redc[1] + redc[2] + redc[3];
    __syncthreads();
    if (total >= 96) lo = mid; else hi = mid - 1;
  }
#pragma unroll
  for (int j = 0; j < 8; ++j) {
    if (key[j] >= lo) {
      const unsigned pos = atomicAdd(&ccnt, 1u);
      if (pos < 160u) cand[pos] = tid + 256 * j;
    }
  }
  __syncthreads();
  const int cnt = (int)(ccnt < 160u ? ccnt : 160u);
  // exact fp32 rescore of candidates
  const int wv = tid >> 6, l = tid & 63;
  for (int ci = wv; ci < cnt; ci += 4) {
    const float* Wr = Wr2 + (size_t)cand[ci] * 512;
    float s = 0.f;
#pragma unroll
    for (int j = 0; j < 8; ++j) s = fmaf(Wr[l + 64 * j], hs[l + 64 * j], s);
#pragma unroll
    for (int m = 1; m < 64; m <<= 1) s += __shfl_xor(s, m);
    if (l == 0) cex[ci] = s;
  }
  __syncthreads();
  // exact top-64 among cnt candidates
  unsigned k2 = 0u;
  int myidx = -1;
  const bool valid = tid < cnt;
  if (valid) {
    const unsigned u = __float_as_uint(cex[tid]);
    k2 = (u & 0x80000000u) ? ~u : (u | 0x80000000u);
    myidx = cand[tid];
  }
  if (tid == 0) { cg_cnt = 0u; ec = 0u; }
  lo = 0u; hi = 0xFFFFFFFFu;
  while (lo < hi) {
    const unsigned mid = (unsigned)(((unsigned long long)lo + hi + 1ull) >> 1);
    int c = (valid && k2 >= mid) ? 1 : 0;
#pragma unroll
    for (int m = 1; m < 64; m <<= 1) c += __shfl_xor(c, m);
    if ((tid & 63) == 0) redc[tid >> 6] = c;
    __syncthreads();
    const int total = redc[0] + redc[1] + redc[2] + redc[3];
    __syncthreads();
    if (total >= 64) lo = mid; else hi = mid - 1;
  }
  if (valid && k2 > lo) {
    const unsigned pos = atomicAdd(&cg_cnt, 1u);
    idxout[(size_t)t * 64 + pos] = myidx;
  } else if (valid && k2 == lo) {
    const unsigned e = atomicAdd(&ec, 1u);
    if (e < 64u) eqbuf[e] = myidx;
  }
  __syncthreads();
  if (tid == 0) {
    const int cg = (int)cg_cnt;
    int ne = (int)ec; if (ne > 64) ne = 64;
    const int need = 64 - cg;
    for (int i = 1; i < ne; ++i) {
      const int v = eqbuf[i];
      int j = i - 1;
      while (j >= 0 && eqbuf[j] > v) { eqbuf[j + 1] = eqbuf[j]; --j; }
      eqbuf[j + 1] = v;
    }
    for (int i = 0; i < need; ++i) idxout[(size_t)t * 64 + cg + i] = eqbuf[i];
  }
}

// ---------------- act[t][k] = gelu(dot(x[t], W_in[idx[t][k]])) ----------------
__global__ __launch_bounds__(256) void k_act(const float* __restrict__ x,
                                             const float* __restrict__ W_in,
                                             const int* __restrict__ idx,
                                             float* __restrict__ act) {
  __shared__ float xs[512];
  const int t = blockIdx.x, tid = threadIdx.x;
  xs[tid] = x[(size_t)t * 512 + tid];
  xs[tid + 256] = x[(size_t)t * 512 + 256 + tid];
  __syncthreads();
  const int w = tid >> 6, l = tid & 63;
  for (int q = 0; q < 16; ++q) {
    const int k = w * 16 + q;
    const int n = idx[(size_t)t * 64 + k];
    const float* Wr = W_in + (size_t)n * 512;
    float s = 0.f;
#pragma unroll
    for (int j = 0; j < 8; ++j) s = fmaf(Wr[l + 64 * j], xs[l + 64 * j], s);
#pragma unroll
    for (int m = 1; m < 64; m <<= 1) s += __shfl_xor(s, m);
    if (l == 0) act[(size_t)t * 64 + k] = gelu_fast(s);
  }
}

// ---------------- fused phi, MFMA (one token per block) ----------------
__global__ __launch_bounds__(256, 1) void k_phi(
    const float* __restrict__ nvphi, const float* __restrict__ pW1,
    const float* __restrict__ pln1_g, const float* __restrict__ pln1_b,
    const u16* __restrict__ pW2T, const float* __restrict__ pb2,
    const float* __restrict__ pln2_g, const float* __restrict__ pln2_b,
    const int* __restrict__ idx, const float* __restrict__ act,
    float* __restrict__ aggp) {
  __shared__ __align__(16) u16 h1s[64 * 264];
  __shared__ __align__(16) u16 Bs[64 * 264];
  __shared__ float aggbuf[4 * 256];
  __shared__ int idxs[64];
  __shared__ float acts[64];
  const int tid = threadIdx.x;
  const int t = blockIdx.x;
  const int w = tid >> 6, lane = tid & 63;
  const int q = lane >> 4, c = lane & 15;
  if (tid < 64) {
    idxs[tid] = idx[(size_t)t * 64 + tid];
    acts[tid] = act[(size_t)t * 64 + tid];
  }
  __syncthreads();
  {
    f32x4 w4[4], g1[4], b1[4];
#pragma unroll
    for (int j = 0; j < 4; ++j) {
      w4[j] = *(const f32x4*)&pW1[128 * 256 + c * 16 + j * 4];
      g1[j] = *(const f32x4*)&pln1_g[c * 16 + j * 4];
      b1[j] = *(const f32x4*)&pln1_b[c * 16 + j * 4];
    }
#pragma unroll 1
    for (int rd = 0; rd < 4; ++rd) {
      const int p = w * 16 + rd * 4 + q;
      const int n = idxs[p];
      const float av = acts[p];
      f32x4 v[4];
      float s = 0.f, s2 = 0.f;
#pragma unroll
      for (int j = 0; j < 4; ++j) {
        const f32x4 nv = *(const f32x4*)&nvphi[(size_t)n * 256 + c * 16 + j * 4];
#pragma unroll
        for (int u = 0; u < 4; ++u) {
          v[j][u] = nv[u] + av * w4[j][u];
          s += v[j][u];
          s2 = fmaf(v[j][u], v[j][u], s2);
        }
      }
#pragma unroll
      for (int m = 1; m < 16; m <<= 1) { s += __shfl_xor(s, m); s2 += __shfl_xor(s2, m); }
      const float mu = s * (1.f / 256.f);
      const float var = fmaxf(s2 * (1.f / 256.f) - mu * mu, 0.f);
      const float rstd = 1.f / sqrtf(var + 1e-5f);
      short8 lo, hi;
#pragma unroll
      for (int j = 0; j < 4; ++j)
#pragma unroll
        for (int u = 0; u < 4; ++u) {
          const float hv = gelu_fast((v[j][u] - mu) * rstd * g1[j][u] + b1[j][u]);
          if (j < 2) lo[j * 4 + u] = (short)f2bf(hv);
          else       hi[(j - 2) * 4 + u] = (short)f2bf(hv);
        }
      *(short8*)&h1s[p * 264 + c * 16] = lo;
      *(short8*)&h1s[p * 264 + c * 16 + 8] = hi;
    }
  }
  __syncthreads();
  short8 afr[8];
#pragma unroll
  for (int ks = 0; ks < 8; ++ks)
    afr[ks] = *(const short8*)&h1s[(w * 16 + c) * 264 + ks * 32 + q * 8];
  f32x4 acc[16];
#pragma unroll
  for (int nt = 0; nt < 16; ++nt) {
    const float bz = pb2[nt * 16 + c];
    acc[nt] = (f32x4){bz, bz, bz, bz};
  }
#pragma unroll
  for (int ch = 0; ch < 4; ++ch) {
    __syncthreads();
#pragma unroll
    for (int i = 0; i < 8; ++i) {
      const int cidx = i * 256 + tid;
      const int n = cidx >> 5, kc = cidx & 31;
      *(i32x4*)&Bs[n * 264 + kc * 8] =
          *(const i32x4*)&pW2T[(size_t)(ch * 64 + n) * 256 + kc * 8];
    }
    __syncthreads();
#pragma unroll
    for (int t4 = 0; t4 < 4; ++t4) {
      const int nt = ch * 4 + t4;
#pragma unroll
      for (int ks = 0; ks < 8; ++ks) {
        const short8 bfr = *(const short8*)&Bs[(t4 * 16 + c) * 264 + ks * 32 + q * 8];
        acc[nt] = __builtin_amdgcn_mfma_f32_16x16x32_bf16(afr[ks], bfr, acc[nt], 0, 0, 0);
      }
    }
  }
  float g2v[16], b2v[16];
#pragma unroll
  for (int nt = 0; nt < 16; ++nt) {
    g2v[nt] = pln2_g[nt * 16 + c];
    b2v[nt] = pln2_b[nt * 16 + c];
  }
  float aggl[16];
#pragma unroll
  for (int nt = 0; nt < 16; ++nt) aggl[nt] = 0.f;
#pragma unroll
  for (int reg = 0; reg < 4; ++reg) {
    float s = 0.f, s2 = 0.f;
#pragma unroll
    for (int nt = 0; nt < 16; ++nt) {
      const float vv = acc[nt][reg];
      s += vv;
      s2 = fmaf(vv, vv, s2);
    }
#pragma unroll
    for (int m = 1; m < 16; m <<= 1) { s += __shfl_xor(s, m); s2 += __shfl_xor(s2, m); }
    const float mu = s * (1.f / 256.f);
    const float var = fmaxf(s2 * (1.f / 256.f) - mu * mu, 0.f);
    const float rstd = 1.f / sqrtf(var + 1e-5f);
#pragma unroll
    for (int nt = 0; nt < 16; ++nt) {
      const float vv = acc[nt][reg];
      aggl[nt] += (vv - mu) * rstd * g2v[nt] + b2v[nt];
    }
  }
#pragma unroll
  for (int nt = 0; nt < 16; ++nt) {
    float vs = aggl[nt];
    vs += __shfl_xor(vs, 16);
    vs += __shfl_xor(vs, 32);
    if (q == 0) aggbuf[w * 256 + nt * 16 + c] = vs;
  }
  __syncthreads();
  aggp[(size_t)t * 256 + tid] =
      aggbuf[tid] + aggbuf[256 + tid] + aggbuf[512 + tid] + aggbuf[768 + tid];
}

// ---------------- r = LN(aggp[t]) over 256 -> split bf16 hi/lo ----------------
__global__ __launch_bounds__(256) void k_rln(const float* __restrict__ aggp,
                                             const float* __restrict__ g,
                                             const float* __restrict__ b,
                                             u16* __restrict__ rh,
                                             u16* __restrict__ rl) {
  __shared__ float red[8];
  const int t = blockIdx.x, tid = threadIdx.x;
  const float v = aggp[(size_t)t * 256 + tid];
  float s = v, s2 = v * v;
  waveRed2(s, s2);
  if ((tid & 63) == 0) { red[(tid >> 6) * 2] = s; red[(tid >> 6) * 2 + 1] = s2; }
  __syncthreads();
  s = red[0] + red[2] + red[4] + red[6];
  s2 = red[1] + red[3] + red[5] + red[7];
  const float mu = s * (1.f / 256.f);
  const float var = fmaxf(s2 * (1.f / 256.f) - mu * mu, 0.f);
  const float rstd = 1.f / sqrtf(var + 1e-5f);
  const float y = (v - mu) * rstd * g[tid] + b[tid];
  const u16 hv = f2bf(y);
  rh[(size_t)t * 256 + tid] = hv;
  rl[(size_t)t * 256 + tid] = f2bf(y - bf2f(hv));
}

// ---------------- launch ----------------
extern "C" void kernel_launch(void* const* d_in, const int* in_sizes, int n_in,
                              void* d_out, int out_size, void* d_ws, size_t ws_size,
                              hipStream_t stream) {
  const float* x = (const float*)d_in[0];
  const float* W_in = (const float*)d_in[1];
  const float* nv = (const float*)d_in[2];
  const float* Wr1 = (const float*)d_in[3];
  const float* Wr2 = (const float*)d_in[4];
  const float* rn_g = (const float*)d_in[5];
  const float* rn_b = (const float*)d_in[6];
  const float* pW1 = (const float*)d_in[7];
  const float* pb1 = (const float*)d_in[8];
  const float* pln1_g = (const float*)d_in[9];
  const float* pln1_b = (const float*)d_in[10];
  const float* pW2 = (const float*)d_in[11];
  const float* pb2 = (const float*)d_in[12];
  const float* pln2_g = (const float*)d_in[13];
  const float* pln2_b = (const float*)d_in[14];
  const float* rln_g = (const float*)d_in[15];
  const float* rln_b = (const float*)d_in[16];
  const float* rW1 = (const float*)d_in[17];
  const float* rb1 = (const float*)d_in[18];
  const float* rW2 = (const float*)d_in[19];
  const float* rb2 = (const float*)d_in[20];
  float* out = (float*)d_out;
  const int T = in_sizes[0] / 512;  // 4096

  float* ws = (float*)d_ws;
  float* xln = ws;    ws += (size_t)T * 512;
  float* h = ws;      ws += (size_t)T * 512;
  float* nvphi = ws;  ws += (size_t)2048 * 256;
  float* actb = ws;   ws += (size_t)T * 64;
  float* aggp = ws;   ws += (size_t)T * 256;
  int* idx = (int*)ws;   ws += (size_t)T * 64;
  u16* scoresb = (u16*)ws; ws += (size_t)T * 2048 / 2;
  u16* hb = (u16*)ws;    ws += (size_t)T * 512 / 2;
  u16* Wr2b = (u16*)ws;  ws += (size_t)2048 * 512 / 2;
  u16* pW2T = (u16*)ws;  ws += (size_t)2048 * 256 / 2;
  u16* rh = (u16*)ws;    ws += (size_t)T * 256 / 2;
  u16* rl = (u16*)ws;    ws += (size_t)T * 256 / 2;
  u16* t1h = (u16*)ws;   ws += (size_t)T * 512 / 2;
  u16* t1l = (u16*)ws;   ws += (size_t)T * 512 / 2;
  u16* rW1Th = (u16*)ws; ws += (size_t)512 * 256 / 2;
  u16* rW1Tl = (u16*)ws; ws += (size_t)512 * 256 / 2;
  u16* rW2Th = (u16*)ws; ws += (size_t)512 * 512 / 2;
  u16* rW2Tl = (u16*)ws; ws += (size_t)512 * 512 / 2;

  // param converts
  k_cvt<<<2048 * 512 / 256, 256, 0, stream>>>(Wr2, Wr2b);
  k_splitT<<<512, 256, 0, stream>>>(rW1, rW1Th, rW1Tl, 256, 512);
  k_splitT<<<512, 256, 0, stream>>>(rW2, rW2Th, rW2Tl, 512, 512);
  k_nvphi<<<2048, 256, 0, stream>>>(nv, pW1, pb1, nvphi);
  k_pw2t<<<256, 256, 0, stream>>>(pW2, pW2T);
  // router: exact fp32 h (+ bf16 copy), approx bf16 scores, exact rescore topk
  k_ln512<<<T, 256, 0, stream>>>(x, rn_g, rn_b, xln);
  gemm_bt<2, true><<<dim3(512 / 64, T / 64), 256, 0, stream>>>(
      xln, Wr1, h, hb, T, 512, 512);
  gemm_mf<false, 0, false, 1><<<dim3(2048 / 128, T / 64), 256, 0, stream>>>(
      hb, nullptr, Wr2b, nullptr, nullptr, scoresb, nullptr, T, 2048, 512);
  k_topk_rs<<<T, 256, 0, stream>>>(scoresb, h, Wr2, idx);
  // experts
  k_act<<<T, 256, 0, stream>>>(x, W_in, idx, actb);
  k_phi<<<T, 256, 0, stream>>>(nvphi, pW1, pln1_g, pln1_b, pW2T, pb2, pln2_g,
                               pln2_b, idx, actb, aggp);
  k_rln<<<T, 256, 0, stream>>>(aggp, rln_g, rln_b, rh, rl);
  // rho: split-bf16 3-MFMA (fp32-class values)
  gemm_mf<true, 1, true, 2><<<dim3(512 / 128, T / 64), 256, 0, stream>>>(
      rh, rl, rW1Th, rW1Tl, rb1, t1h, t1l, T, 512, 256);
  gemm_mf<true, 0, true, 0><<<dim3(512 / 128, T / 64), 256, 0, stream>>>(
      t1h, t1l, rW2Th, rW2Tl, rb2, out, nullptr, T, 512, 512);
}